// Round 4
// baseline (63.194 us; speedup 1.0000x reference)
//
#include <hip/hip_runtime.h>
#include <hip/hip_bf16.h>

typedef __attribute__((ext_vector_type(8))) short bf16x8;
typedef __attribute__((ext_vector_type(4))) float f32x4;

#define NB   4
#define NN   2048
#define FIN  256
#define FOUT 128
#define SPLIT 4
#define JCH  (NN / SPLIT)      // 512 j per wave-task
#define NSTEP (JCH / 64)       // 8 steps of 64 j

__device__ __forceinline__ unsigned short f2bf(float f) {
    unsigned int u = __builtin_bit_cast(unsigned int, f);
    u += 0x7fffu + ((u >> 16) & 1u);
    return (unsigned short)(u >> 16);
}

// ---------------- Kernel 0: WT[o][k] bf16 from W[k][o] f32 ----------------
__global__ __launch_bounds__(256) void k_wt(const float* __restrict__ W,
                                            unsigned short* __restrict__ WT) {
    int idx = blockIdx.x * 256 + threadIdx.x;      // 32768 = 128*256
    int k = idx & 255, o = idx >> 8;
    WT[idx] = f2bf(W[k * FOUT + o]);
}

// ---------------- Kernel 1: Wh = h@W (MFMA), writes WhT bf16 + s1,s2 ------
__global__ __launch_bounds__(256) void k_wh(const float* __restrict__ h,
                                            const float* __restrict__ a,
                                            const unsigned short* __restrict__ WT,
                                            unsigned short* __restrict__ WhT,
                                            float* __restrict__ s1,
                                            float* __restrict__ s2) {
    __shared__ unsigned short hs[16][264];
    __shared__ float s1w[4][16], s2w[4][16];
    int t = threadIdx.x, blk = blockIdx.x;
    int nglob0 = blk * 16;
    int b = nglob0 >> 11;

    const float4* h4 = (const float4*)h + (size_t)blk * 1024;
    #pragma unroll
    for (int i = 0; i < 4; ++i) {
        int idx = i * 256 + t;
        float4 v = h4[idx];
        int row = idx >> 6, c4 = (idx & 63) * 4;
        unsigned int lo = (unsigned int)f2bf(v.x) | ((unsigned int)f2bf(v.y) << 16);
        unsigned int hi = (unsigned int)f2bf(v.z) | ((unsigned int)f2bf(v.w) << 16);
        *(uint2*)&hs[row][c4] = make_uint2(lo, hi);
    }
    __syncthreads();

    int w = t >> 6, l = t & 63, lr = l & 15, lk = l >> 4;
    float a1v[2], a2v[2];
    #pragma unroll
    for (int j = 0; j < 2; ++j) {
        a1v[j] = a[(w * 2 + j) * 16 + lr];
        a2v[j] = a[FOUT + (w * 2 + j) * 16 + lr];
    }
    f32x4 acc[2] = {{0.f,0.f,0.f,0.f},{0.f,0.f,0.f,0.f}};

    #pragma unroll
    for (int kk = 0; kk < 8; ++kk) {
        int k0 = kk * 32;
        bf16x8 af = *(const bf16x8*)&hs[lr][k0 + lk * 8];
        #pragma unroll
        for (int j = 0; j < 2; ++j) {
            bf16x8 bf = *(const bf16x8*)(WT + ((w * 2 + j) * 16 + lr) * 256 + k0 + lk * 8);
            acc[j] = __builtin_amdgcn_mfma_f32_16x16x32_bf16(af, bf, acc[j], 0, 0, 0);
        }
    }

    int nn0 = (nglob0 & 2047) + lk * 4;
    float v1[4] = {0.f,0.f,0.f,0.f}, v2[4] = {0.f,0.f,0.f,0.f};
    #pragma unroll
    for (int j = 0; j < 2; ++j) {
        float x0 = acc[j][0], x1 = acc[j][1], x2 = acc[j][2], x3 = acc[j][3];
        ushort4 pk;
        pk.x = f2bf(x0); pk.y = f2bf(x1); pk.z = f2bf(x2); pk.w = f2bf(x3);
        *(ushort4*)(WhT + (size_t)(b * FOUT + (w * 2 + j) * 16 + lr) * NN + nn0) = pk;
        v1[0] += x0 * a1v[j]; v1[1] += x1 * a1v[j]; v1[2] += x2 * a1v[j]; v1[3] += x3 * a1v[j];
        v2[0] += x0 * a2v[j]; v2[1] += x1 * a2v[j]; v2[2] += x2 * a2v[j]; v2[3] += x3 * a2v[j];
    }
    #pragma unroll
    for (int m = 1; m < 16; m <<= 1) {
        #pragma unroll
        for (int r = 0; r < 4; ++r) {
            v1[r] += __shfl_xor(v1[r], m);
            v2[r] += __shfl_xor(v2[r], m);
        }
    }
    if (lr == 0) {
        #pragma unroll
        for (int r = 0; r < 4; ++r) {
            s1w[w][lk * 4 + r] = v1[r];
            s2w[w][lk * 4 + r] = v2[r];
        }
    }
    __syncthreads();
    if (t < 16) {
        s1[nglob0 + t] = s1w[0][t] + s1w[1][t] + s1w[2][t] + s1w[3][t];
        s2[nglob0 + t] = s2w[0][t] + s2w[1][t] + s2w[2][t] + s2w[3][t];
    }
}

// ---------------- Kernel 2: wave-autonomous partial attention -------------
// 2048 blocks x 64 threads (1 wave). No inter-wave sync; main loop has NO
// barriers (R3 lesson: barrier lockstep capped adj stream at 1 TB/s).
// Each wave: 16 i-rows x 512 j, all 128 o. P-frags built in registers.
__global__ __launch_bounds__(64) void k_attn(const int* __restrict__ adj,
                                             const unsigned short* __restrict__ WhT,
                                             const float* __restrict__ s1,
                                             const float* __restrict__ s2,
                                             float* __restrict__ num,
                                             float* __restrict__ Zp) {
    __shared__ float hS[16][132];

    int l = threadIdx.x, lr = l & 15, lk = l >> 4;
    int wid = blockIdx.x;
    int part = wid >> 9;                           // 0..3
    int rem  = wid & 511;
    int b    = rem >> 7;
    int i0   = (rem & 127) * 16;
    int j0   = part * JCH;

    float s1r = s1[b * NN + i0 + lr];
    const int*   adjRow = adj + (size_t)(b * NN + i0 + lr) * NN + j0;  // lane's row
    const float* s2b    = s2 + b * NN + j0;
    const unsigned short* Bb = WhT + (size_t)(b * FOUT + lr) * NN + j0;

    f32x4 acc[8];
    #pragma unroll
    for (int ot = 0; ot < 8; ++ot) acc[ot] = (f32x4){0.f, 0.f, 0.f, 0.f};
    float zacc = 0.f;

    // prefetch step 0 adj: lane's 16 ints (k-slots lk*8..+7 of both halves)
    const int* ap = adjRow + lk * 8;
    int4 a0lo = *(const int4*)(ap);
    int4 a0hi = *(const int4*)(ap + 4);
    int4 a1lo = *(const int4*)(ap + 32);
    int4 a1hi = *(const int4*)(ap + 36);

    for (int step = 0; step < NSTEP; ++step) {
        int jb = step * 64;
        int4 c0lo = a0lo, c0hi = a0hi, c1lo = a1lo, c1hi = a1hi;
        if (step < NSTEP - 1) {                    // prefetch next step (HBM stream)
            const int* an = adjRow + jb + 64 + lk * 8;
            a0lo = *(const int4*)(an);
            a0hi = *(const int4*)(an + 4);
            a1lo = *(const int4*)(an + 32);
            a1hi = *(const int4*)(an + 36);
        }

        // s2 slots (L2-resident, 8 KB per b)
        const float* sp = s2b + jb + lk * 8;
        float4 t0lo = *(const float4*)(sp);
        float4 t0hi = *(const float4*)(sp + 4);
        float4 t1lo = *(const float4*)(sp + 32);
        float4 t1hi = *(const float4*)(sp + 36);

        // build P-frags in registers
        int   am[16] = {c0lo.x, c0lo.y, c0lo.z, c0lo.w, c0hi.x, c0hi.y, c0hi.z, c0hi.w,
                        c1lo.x, c1lo.y, c1lo.z, c1lo.w, c1hi.x, c1hi.y, c1hi.z, c1hi.w};
        float sv[16] = {t0lo.x, t0lo.y, t0lo.z, t0lo.w, t0hi.x, t0hi.y, t0hi.z, t0hi.w,
                        t1lo.x, t1lo.y, t1lo.z, t1lo.w, t1hi.x, t1hi.y, t1hi.z, t1hi.w};
        unsigned int pw[8];
        #pragma unroll
        for (int q = 0; q < 8; ++q) {
            float e0 = s1r + sv[2 * q];
            float e1 = s1r + sv[2 * q + 1];
            e0 = fmaxf(e0, 0.2f * e0);
            e1 = fmaxf(e1, 0.2f * e1);
            float p0 = (am[2 * q] > 0)     ? __expf(e0) : 0.f;
            float p1 = (am[2 * q + 1] > 0) ? __expf(e1) : 0.f;
            zacc += p0 + p1;
            pw[q] = (unsigned int)f2bf(p0) | ((unsigned int)f2bf(p1) << 16);
        }
        bf16x8 pa0 = __builtin_bit_cast(bf16x8, (uint4){pw[0], pw[1], pw[2], pw[3]});
        bf16x8 pa1 = __builtin_bit_cast(bf16x8, (uint4){pw[4], pw[5], pw[6], pw[7]});

        // 16 MFMAs over 8 o-tiles (B-frags L2/L3-resident, 2 MB total)
        #pragma unroll
        for (int ot = 0; ot < 8; ++ot) {
            const unsigned short* bp = Bb + (size_t)ot * 16 * NN + jb + lk * 8;
            bf16x8 b0 = *(const bf16x8*)bp;
            bf16x8 b1 = *(const bf16x8*)(bp + 32);
            acc[ot] = __builtin_amdgcn_mfma_f32_16x16x32_bf16(pa0, b0, acc[ot], 0, 0, 0);
            acc[ot] = __builtin_amdgcn_mfma_f32_16x16x32_bf16(pa1, b1, acc[ot], 0, 0, 0);
        }
    }

    // Z partial: sum the 4 lk-lanes of each row
    zacc += __shfl_xor(zacc, 16);
    zacc += __shfl_xor(zacc, 32);
    if (lk == 0) Zp[(size_t)(part * NB + b) * NN + i0 + lr] = zacc;

    // stage numerators in (wave-private) LDS, coalesced float4 stores
    #pragma unroll
    for (int ot = 0; ot < 8; ++ot)
        #pragma unroll
        for (int r = 0; r < 4; ++r)
            hS[lk * 4 + r][ot * 16 + lr] = acc[ot][r];
    __syncthreads();

    float* np = num + ((size_t)(part * NB + b) * NN + i0) * FOUT;
    #pragma unroll
    for (int i = 0; i < 8; ++i) {
        int idx = i * 64 + l;
        int row = idx >> 5, c4 = (idx & 31) * 4;
        *(float4*)(np + row * FOUT + c4) = *(const float4*)&hS[row][c4];
    }
}

// ---------------- Kernel 3: reduce splits + LayerNorm + GELU --------------
__global__ __launch_bounds__(256) void k_final(const float* __restrict__ num,
                                               const float* __restrict__ Zp,
                                               const float* __restrict__ gamma,
                                               const float* __restrict__ beta,
                                               float* __restrict__ out) {
    int t = threadIdx.x, bi = blockIdx.x;
    int rowA = t >> 5;
    int c0 = (t & 31) * 4;
    size_t gn = (size_t)bi * 8 + rowA;
    int b = (int)(gn >> 11), n = (int)(gn & 2047);

    float Z = 0.f;
    #pragma unroll
    for (int p = 0; p < SPLIT; ++p) Z += Zp[(size_t)(p * NB + b) * NN + n];

    float x[4] = {0.f, 0.f, 0.f, 0.f};
    #pragma unroll
    for (int p = 0; p < SPLIT; ++p) {
        const float* np = num + ((size_t)(p * NB + b) * NN + n) * FOUT + c0;
        float4 v0 = *(const float4*)np;
        x[0] += v0.x; x[1] += v0.y; x[2] += v0.z; x[3] += v0.w;
    }
    float rz = 1.f / Z;
    #pragma unroll
    for (int i = 0; i < 4; ++i) x[i] *= rz;

    float sm = 0.f, sq = 0.f;
    #pragma unroll
    for (int i = 0; i < 4; ++i) { sm += x[i]; sq += x[i] * x[i]; }
    #pragma unroll
    for (int m = 1; m < 32; m <<= 1) {
        sm += __shfl_xor(sm, m);
        sq += __shfl_xor(sq, m);
    }
    float mu  = sm * (1.f / 128.f);
    float var = sq * (1.f / 128.f) - mu * mu;
    float rs  = rsqrtf(var + 1e-5f);
    float4 g0 = *(const float4*)(gamma + c0);
    float4 e0 = *(const float4*)(beta + c0);
    float gg[4] = {g0.x, g0.y, g0.z, g0.w};
    float bb[4] = {e0.x, e0.y, e0.z, e0.w};
    float y[4];
    #pragma unroll
    for (int i = 0; i < 4; ++i) {
        float v = (x[i] - mu) * rs * gg[i] + bb[i];
        y[i] = 0.5f * v * (1.f + erff(v * 0.70710678118f));
    }
    float* op = out + gn * FOUT + c0;
    *(float4*)op = make_float4(y[0], y[1], y[2], y[3]);
}

// ---------------- launcher ----------------
extern "C" void kernel_launch(void* const* d_in, const int* in_sizes, int n_in,
                              void* d_out, int out_size, void* d_ws, size_t ws_size,
                              hipStream_t stream) {
    const float* h     = (const float*)d_in[0];
    const int*   adj   = (const int*)d_in[1];
    const float* W     = (const float*)d_in[2];
    const float* a     = (const float*)d_in[3];
    const float* gamma = (const float*)d_in[4];
    const float* beta  = (const float*)d_in[5];
    float* out = (float*)d_out;

    char* ws = (char*)d_ws;
    unsigned short* WT  = (unsigned short*)ws;                       // 64 KiB
    unsigned short* WhT = (unsigned short*)(ws + (1u << 16));        // 2 MiB
    float* s1 = (float*)(ws + 2162688);                              // 32 KiB
    float* s2 = (float*)(ws + 2195456);                              // 32 KiB
    float* Zp = (float*)(ws + 2228224);                              // 128 KiB
    float* num = (float*)(ws + 2359296);                             // 16 MiB

    hipLaunchKernelGGL(k_wt,    dim3(128),  dim3(256), 0, stream, W, WT);
    hipLaunchKernelGGL(k_wh,    dim3(512),  dim3(256), 0, stream, h, a, WT, WhT, s1, s2);
    hipLaunchKernelGGL(k_attn,  dim3(2048), dim3(64),  0, stream, adj, WhT, s1, s2, num, Zp);
    hipLaunchKernelGGL(k_final, dim3(1024), dim3(256), 0, stream, num, Zp, gamma, beta, out);
}